// Round 6
// baseline (133155.811 us; speedup 1.0000x reference)
//
#include <hip/hip_runtime.h>
#include <stdint.h>

// AutoRegressiveModel: 47 outer x 512 inner sequential LSTM steps (mid=256),
// Bernoulli sampling bit-matches JAX threefry2x32 (partitionable mode).
//
// R8 = R7 (same-XCD L2 h-exchange via sc0) with the R7 showstopper fixed:
//  - R7's hipMemsetAsync zeroed ws+512*256+256 (u64) == middle of obsbuf,
//    NOT p_prog (which is at ws+512*256+1024 u64). Election state stayed
//    stale -> dispatch>=2: all candidates got idx>=16 -> zero workers ->
//    sampler spun forever -> hang. R8 zeroes the REAL ctrl region and the
//    h_l2 ring (depth 16->8, 16KB; depth-2 provably safe since producing
//    h_s implies all blocks finished s-1, max lag 1 step).
//  - s_getreg hwreg(20,0,32) numeric form (HW_REG_XCC_ID=20 on gfx94x+);
//    no symbolic-name assembler risk. A misread value only mis-groups
//    blocks -> sc0 self-test fails -> verified agent-scope fallback.
//
// Structure (established R2-R5 A/B series): ~2000cy of the 3170cy/step is
// agent-scope (L3 coherence point) store->poll latency. 16 worker blocks
// co-located on ONE XCD exchange h through that XCD's L2 with sc0 ops
// (~200cy/hop). Election by pigeonhole over 128 candidates; sc0 coherence
// self-test with timeout -> unanimous fallback on any anomaly; liveness
// escape via the agent-scope copy every 32 spins (cannot hang).

#define MID      256
#define NOUT     48
#define NSEQ     512
#define NOUTER   47
#define NSTEP    (NOUTER * NSEQ)   // 24064
#define NBLK     16
#define NCAND    128
#define MAGIC_V  0x1234ABCDu
#define LOG2E    1.4426950408889634f

typedef __attribute__((ext_vector_type(4))) float f32x4;

#define LD_REL(p) __hip_atomic_load((p), __ATOMIC_RELAXED, __HIP_MEMORY_SCOPE_AGENT)

// LDS-only barrier: order LDS ops before the barrier, skip vmcnt drain.
#define LDS_BARRIER() do {                                          \
    asm volatile("s_waitcnt lgkmcnt(0)\n\ts_barrier" ::: "memory"); \
    __builtin_amdgcn_sched_barrier(0);                              \
  } while (0)

__device__ __forceinline__ uint32_t rotl32(uint32_t x, int d) {
  return (x << d) | (x >> (32 - d));
}

// Exact JAX threefry2x32 (20 rounds).
__device__ __forceinline__ void threefry2x32(uint32_t k0, uint32_t k1,
                                             uint32_t x0, uint32_t x1,
                                             uint32_t& o0, uint32_t& o1) {
  uint32_t ks2 = k0 ^ k1 ^ 0x1BD11BDAu;
  uint32_t v0 = x0 + k0, v1 = x1 + k1;
#define TF_R(r) { v0 += v1; v1 = rotl32(v1, r); v1 ^= v0; }
  TF_R(13) TF_R(15) TF_R(26) TF_R(6)
  v0 += k1;  v1 += ks2 + 1u;
  TF_R(17) TF_R(29) TF_R(16) TF_R(24)
  v0 += ks2; v1 += k0 + 2u;
  TF_R(13) TF_R(15) TF_R(26) TF_R(6)
  v0 += k0;  v1 += k1 + 3u;
  TF_R(17) TF_R(29) TF_R(16) TF_R(24)
  v0 += k1;  v1 += ks2 + 4u;
  TF_R(13) TF_R(15) TF_R(26) TF_R(6)
  v0 += ks2; v1 += k0 + 5u;
#undef TF_R
  o0 = v0; o1 = v1;
}

// Accurate sigmoid for the sampler (off critical path).
__device__ __forceinline__ float sigf(float x) { return 1.0f / (1.0f + expf(-x)); }

__device__ __forceinline__ uint64_t packht(float h, uint32_t tag) {
  return ((uint64_t)tag << 32) | (uint64_t)__float_as_uint(h);
}

__global__ __launch_bounds__(256, 1)
void arlstm_kernel(const float* __restrict__ W_ih, const float* __restrict__ W_hh,
                   const float* __restrict__ b_ih, const float* __restrict__ b_hh,
                   const float* __restrict__ W_out, const float* __restrict__ b_out,
                   float* __restrict__ out, uint64_t* __restrict__ ws) {
  // ws layout (u64 units):
  //   [0, 131072)       h_hist [512][256] tagged (agent; sampler path)
  //   [131072, 132096)  obsbuf [2][512][2] f32
  //   [132096, 132160)  ctrl: p_prog[4], magic, cand_cnt[8], winner, salt,
  //                     verdict[16], test_a[16]   (512 B, memset-cleared)
  //   [132160, 134208)  h_l2 [8][256] tagged ring (sc0 world, memset-cleared)
  uint64_t* h_hist = ws;
  float*    obsbuf = (float*)(ws + 512 * 256);
  uint32_t* p_prog = (uint32_t*)(ws + 512 * 256 + 1024);
  uint32_t* magic    = p_prog + 16;
  uint32_t* cand_cnt = p_prog + 17;                       // [8] per-XCD claims
  int*      winner_p = (int*)(p_prog + 25);               // 0=unset, else xcd+1
  uint32_t* salt_p   = p_prog + 26;                       // per-dispatch salt
  uint32_t* verdict  = p_prog + 27;                       // [16] 0=?,1=ok,2=fail
  uint32_t* test_a   = p_prog + 43;                       // [16] sc0 test tokens
  uint64_t* ob64     = (uint64_t*)obsbuf;                 // pair view (8B aligned)
  uint64_t* h_l2     = ws + 512 * 256 + 1024 + 64;        // [8][256] tagged

  const int tid = threadIdx.x;

  __shared__ __align__(16) float hstage[256];
  __shared__ float plds[4][64];
  __shared__ float ring[2][16][2];
  __shared__ float lp_acc[512];
  __shared__ float ent_acc[512];
  __shared__ float red[256];
  __shared__ int role_sh, mode_sh;

  if (blockIdx.x == 0) {
    // ----------------------- init + sampler block -----------------------
    // (ctrl + h_l2 already zeroed by hipMemsetAsync before this kernel)
    __hip_atomic_store(&h_hist[tid], 0ull, __ATOMIC_RELAXED, __HIP_MEMORY_SCOPE_AGENT);
    if (tid == 0)
      __hip_atomic_store(salt_p, (uint32_t)__builtin_amdgcn_s_memrealtime() | 1u,
                         __ATOMIC_RELAXED, __HIP_MEMORY_SCOPE_AGENT);
    out[(tid)       * NOUT] = 0.0f;   // samples column 0 = zeros
    out[(tid + 256) * NOUT] = 0.0f;
    lp_acc[tid] = 0.0f;  lp_acc[tid + 256] = 0.0f;
    ent_acc[tid] = 0.0f; ent_acc[tid + 256] = 0.0f;
    __threadfence();
    __syncthreads();
    if (tid == 0)
      __hip_atomic_store(magic, MAGIC_V, __ATOMIC_RELEASE, __HIP_MEMORY_SCOPE_AGENT);

    const int w    = tid >> 6;   // wave 0..3 handles steps s with (s-1)&3 == w
    const int lane = tid & 63;
    const float wo0 = W_out[lane * 4 + 0], wo1 = W_out[lane * 4 + 1];
    const float wo2 = W_out[lane * 4 + 2], wo3 = W_out[lane * 4 + 3];
    const float bo = b_out[0];

    for (int s = w + 1; s <= NSTEP; s += 4) {
      const int k = (s - 1) >> 9;
      const int t = (s - 1) & 511;
      uint64_t* src = h_hist + (uint64_t)(s & 511) * 256 + lane * 4;
      uint64_t v0, v1, v2, v3;
      for (;;) {
        v0 = LD_REL(src + 0);
        v1 = LD_REL(src + 1);
        v2 = LD_REL(src + 2);
        v3 = LD_REL(src + 3);
        int ok = ((uint32_t)(v0 >> 32) == (uint32_t)s) &
                 ((uint32_t)(v1 >> 32) == (uint32_t)s) &
                 ((uint32_t)(v2 >> 32) == (uint32_t)s) &
                 ((uint32_t)(v3 >> 32) == (uint32_t)s);
        if (__all(ok)) break;
      }
      float zp = fmaf(__uint_as_float((uint32_t)v0), wo0,
                 fmaf(__uint_as_float((uint32_t)v1), wo1,
                 fmaf(__uint_as_float((uint32_t)v2), wo2,
                      __uint_as_float((uint32_t)v3) * wo3)));
      zp += __shfl_xor(zp, 1);
      zp += __shfl_xor(zp, 2);
      zp += __shfl_xor(zp, 4);
      zp += __shfl_xor(zp, 8);
      zp += __shfl_xor(zp, 16);
      zp += __shfl_xor(zp, 32);
      const float p = sigf(zp + bo);

      // JAX partitionable threefry: key_k = tf((0,42),(0,k)); bits = xor of
      // tf(key_k,(0,t)); u = bitcast((bits>>9)|0x3f800000)-1; sample = u < p.
      uint32_t ka, kb, c1, c2;
      threefry2x32(0u, 42u, 0u, (uint32_t)k, ka, kb);
      threefry2x32(ka, kb, 0u, (uint32_t)t, c1, c2);
      const uint32_t bits = c1 ^ c2;
      const float u = __uint_as_float((bits >> 9) | 0x3f800000u) - 1.0f;
      const float smp = (u < p) ? 1.0f : 0.0f;

      if (lane == 0) {
        uint32_t* ob = (uint32_t*)(obsbuf + ((k + 1) & 1) * (512 * 2) + t * 2);
        __hip_atomic_store(&ob[0], __float_as_uint(smp), __ATOMIC_RELAXED, __HIP_MEMORY_SCOPE_AGENT);
        __hip_atomic_store(&ob[1], __float_as_uint(p),   __ATOMIC_RELAXED, __HIP_MEMORY_SCOPE_AGENT);
        __hip_atomic_store(&p_prog[w], (uint32_t)s, __ATOMIC_RELEASE, __HIP_MEMORY_SCOPE_AGENT);
        out[t * NOUT + (k + 1)] = smp;
        const float lg = logf(p), lg1 = log1pf(-p);
        lp_acc[t]  += (smp > 0.5f) ? lg : lg1;
        ent_acc[t] -= (p * lg + (1.0f - p) * lg1);
      }
    }
    __syncthreads();
    // final outputs: logprobs (centered), entropies (mean over 47)
    red[tid] = lp_acc[tid] + lp_acc[tid + 256];
    __syncthreads();
    for (int off = 128; off > 0; off >>= 1) {
      if (tid < off) red[tid] += red[tid + off];
      __syncthreads();
    }
    const float mean = red[0] * (1.0f / 512.0f);
    out[24576 + tid]        = lp_acc[tid]        - mean;
    out[24576 + 256 + tid]  = lp_acc[tid + 256]  - mean;
    out[25088 + tid]        = ent_acc[tid]       * (1.0f / 47.0f);
    out[25088 + 256 + tid]  = ent_acc[tid + 256] * (1.0f / 47.0f);
  } else {
    // ----------------- worker candidate: claim a co-located slot -----------------
    if (tid == 0) {
      while (__hip_atomic_load(magic, __ATOMIC_ACQUIRE, __HIP_MEMORY_SCOPE_AGENT) != MAGIC_V) {}
      uint32_t xcd;
      asm volatile("s_getreg_b32 %0, hwreg(20, 0, 32)" : "=s"(xcd));  // XCC_ID
      xcd &= 7u;
      int idx = (int)atomicAdd(&cand_cnt[xcd], 1u);
      int role = -1;
      if (idx < NBLK) {
        if (idx == NBLK - 1) atomicCAS(winner_p, 0, (int)xcd + 1);  // 0 = unset
        int wv;
        while ((wv = (int)__hip_atomic_load((uint32_t*)winner_p, __ATOMIC_ACQUIRE,
                                            __HIP_MEMORY_SCOPE_AGENT)) == 0) {}
        if (wv == (int)xcd + 1) role = idx;
      }
      role_sh = role;
    }
    __syncthreads();
    const int blk = role_sh;
    if (blk < 0) return;                // loser block: free the CU

    // ---- sc0 coherence self-test among the 16 winners (timeout -> fallback) ----
    if (tid == 0) {
      const uint32_t salt = __hip_atomic_load(salt_p, __ATOMIC_RELAXED, __HIP_MEMORY_SCOPE_AGENT);
      const uint32_t tok = salt ^ (0x9E3779B9u * (uint32_t)(blk + 1));
      asm volatile("global_store_dword %0, %1, off sc0\n\ts_waitcnt vmcnt(0)"
                   :: "v"(&test_a[blk]), "v"(tok) : "memory");
      int ok = 1;
      for (int j = 0; j < NBLK && ok; ++j) {
        const uint32_t want = salt ^ (0x9E3779B9u * (uint32_t)(j + 1));
        uint64_t t0 = __builtin_amdgcn_s_memrealtime();   // ~100 MHz constant clock
        for (;;) {
          uint32_t tv;
          asm volatile("global_load_dword %0, %1, off sc0\n\ts_waitcnt vmcnt(0)"
                       : "=v"(tv) : "v"(&test_a[j]) : "memory");
          if (tv == want) break;
          if (__builtin_amdgcn_s_memrealtime() - t0 > 10000000ull) { ok = 0; break; }
        }
      }
      __hip_atomic_store(&verdict[blk], ok ? 1u : 2u, __ATOMIC_RELEASE, __HIP_MEMORY_SCOPE_AGENT);
      uint32_t bad = 0;
      for (int j = 0; j < NBLK; ++j) {
        uint32_t vv;
        while ((vv = __hip_atomic_load(&verdict[j], __ATOMIC_ACQUIRE,
                                       __HIP_MEMORY_SCOPE_AGENT)) == 0u) {}
        if (vv == 2u) bad = 1;
      }
      mode_sh = bad ? 0 : 1;
    }
    __syncthreads();
    const bool l2m = (mode_sh != 0);    // true: same-XCD L2 exchange via sc0

    // --------------------------- LSTM worker ---------------------------
    const int part = tid >> 6;          // wave id = column quarter 0..3
    const int r    = tid & 63;          // local row (gate*16 + jloc)
    const int gate = r >> 4;
    const int jloc = r & 15;
    const int row  = gate * 256 + blk * 16 + jloc;

    // W_hh slice in true VGPRs (asm pin prevents rematerialized reloads).
    f32x4 w4[16];
    const f32x4* wsrc = (const f32x4*)(W_hh + row * 256 + part * 64);
#pragma unroll
    for (int i = 0; i < 16; ++i) w4[i] = wsrc[i];
#pragma unroll
    for (int i = 0; i < 16; ++i) asm volatile("" : "+v"(w4[i]));

    // Per-lane epilogue constants (lanes 0..63: lane = gate*16 + j).
    float bb = 0.f, wx0 = 0.f, wx1 = 0.f, mconst = 0.f, ml = 0.f, ad = 0.f;
    if (tid < 64) {
      const int g4 = tid >> 4;
      const int rr = g4 * 256 + blk * 16 + (tid & 15);
      bb  = b_ih[rr] + b_hh[rr];
      wx0 = W_ih[rr * 2 + 0];
      wx1 = W_ih[rr * 2 + 1];
      mconst = (g4 == 2) ? (-2.0f * LOG2E) : (-LOG2E);  // act = ml*sig(sc*x)+ad
      ml     = (g4 == 2) ? 2.0f : 1.0f;
      ad     = (g4 == 2) ? -1.0f : 0.0f;
    }

    if (tid < 16) {  // obs ring: batch 0 (k=0) is all zeros
      ring[0][tid][0] = 0.f; ring[0][tid][1] = 0.f;
      ring[1][tid][0] = 0.f; ring[1][tid][1] = 0.f;
    }
    __syncthreads();

    float c_st = 0.0f;                      // cell state (lanes 0..15)
    const int jglob = blk * 16 + (tid & 15);
    const bool own = (tid >= blk * 16) && (tid < blk * 16 + 16);

    // obs prefetch pipeline state (wave 3, lanes 0..15)
    int      pf_tgt = 0, pf_need = 0;
    uint32_t pf_ppv = 0;
    uint64_t pf_ov  = 0;

    for (int s = 1; s <= NSTEP; ++s) {
      const int ph = (s - 1) & 15;

      // ---- obs prefetch machinery: 3-phase, once per 16 steps (wave 3) ----
      if (part == 3) {
        if (ph == 0) {
          // target steps s+16 .. s+31 (next batch); lane L -> s+16+L
          pf_tgt  = s + 16 + r;
          pf_need = 0;
          if (r < 16 && pf_tgt > NSEQ && pf_tgt <= NSTEP) {
            pf_need = pf_tgt - NSEQ;                 // sampler step required
            pf_ppv  = LD_REL(&p_prog[(pf_need - 1) & 3]);
          }
        } else if (ph == 1) {
          bool ok = (pf_need == 0) || (pf_ppv >= (uint32_t)pf_need);
          while (!__all(ok)) {                       // essentially never taken
            if (!ok) pf_ppv = LD_REL(&p_prog[(pf_need - 1) & 3]);
            ok = (pf_need == 0) || (pf_ppv >= (uint32_t)pf_need);
          }
          pf_ov = 0;
          if (r < 16 && pf_need != 0) {              // flag seen -> data safe
            const int kk = (pf_tgt - 1) >> 9;
            const int tt = (pf_tgt - 1) & 511;
            pf_ov = LD_REL(ob64 + (kk & 1) * 512 + tt);
          }
        } else if (ph == 2) {
          if (r < 16) {
            const int par = (((s - 3) >> 4) + 1) & 1;   // parity of batch b+1
            ring[par][r][0] = __uint_as_float((uint32_t)pf_ov);
            ring[par][r][1] = __uint_as_float((uint32_t)(pf_ov >> 32));
          }
        }
      }

      // ---- stage h_{s-1}: L2-latency poll of the depth-8 tagged ring ----
      // (own-block words arrive via LDS short-circuit; h_0 is all zeros)
      if (s == 1) {
        hstage[tid] = 0.0f;
      } else if (!own) {
        const uint64_t* src  = h_l2 + (uint64_t)((s - 1) & 7) * 256 + tid;
        const uint64_t* srcA = h_hist + (uint64_t)((s - 1) & 511) * 256 + tid;
        const uint32_t want = (uint32_t)(s - 1);
        uint64_t v;
        if (l2m) {
          int spins = 0;
          for (;;) {
            asm volatile("global_load_dwordx2 %0, %1, off sc0\n\ts_waitcnt vmcnt(0)"
                         : "=v"(v) : "v"(src) : "memory");
            if ((uint32_t)(v >> 32) == want) break;
            if (((++spins) & 31) == 0) {     // liveness escape via agent copy
              v = LD_REL(srcA);
              if ((uint32_t)(v >> 32) == want) break;
            }
          }
        } else {
          for (;;) { v = LD_REL(srcA); if ((uint32_t)(v >> 32) == want) break; }
        }
        hstage[tid] = __uint_as_float((uint32_t)v);
      }
      LDS_BARRIER();   // barrier 1: hstage ready (LDS only, no vmcnt drain)

      float a0 = 0.f, a1 = 0.f, a2 = 0.f, a3 = 0.f;
      const f32x4* hs4 = (const f32x4*)(hstage + part * 64);
#pragma unroll
      for (int i = 0; i < 16; ++i) {
        const f32x4 hv = hs4[i];           // same-address broadcast read
        a0 = fmaf(w4[i][0], hv[0], a0);
        a1 = fmaf(w4[i][1], hv[1], a1);
        a2 = fmaf(w4[i][2], hv[2], a2);
        a3 = fmaf(w4[i][3], hv[3], a3);
      }
      plds[part][r] = (a0 + a1) + (a2 + a3);
      LDS_BARRIER();   // barrier 2: plds ready (LDS only)

      if (tid < 64) {
        // One gate per lane: gv = full gate pre-activation.
        const float sx = ring[((s - 1) >> 4) & 1][ph][0];
        const float px = ring[((s - 1) >> 4) & 1][ph][1];
        const float base = wx0 * sx + wx1 * px + bb;
        const float gv = ((plds[0][tid] + plds[1][tid]) +
                          (plds[2][tid] + plds[3][tid])) + base;
        // act = sig(gv) for gates i,f,o; tanh(gv) = 2*sig(2gv)-1 for gate g.
        const float e   = __builtin_amdgcn_exp2f(gv * mconst);
        const float y   = __builtin_amdgcn_rcpf(1.0f + e);
        const float act = __builtin_fmaf(ml, y, ad);
        const int j = tid & 15;
        const float a_f = __shfl(act, j + 16, 64);
        const float a_g = __shfl(act, j + 32, 64);
        const float a_o = __shfl(act, j + 48, 64);
        if (tid < 16) {
          const float t1 = a_f * c_st;
          const float t2 = act * a_g;     // act = sig(i) on lanes 0..15
          c_st = t1 + t2;
          const float ec = __builtin_amdgcn_exp2f(c_st * (-2.0f * LOG2E));
          const float yc = __builtin_amdgcn_rcpf(1.0f + ec);
          const float th = __builtin_fmaf(2.0f, yc, -1.0f);
          const float hnew = a_o * th;
          hstage[jglob] = hnew;           // own-block short-circuit (WAR-safe:
                                          // all step-s reads drained at barrier2)
          const uint64_t pk = packht(hnew, (uint32_t)s);
          uint64_t* dst2 = h_l2 + (uint64_t)(s & 7) * 256 + jglob;
          if (l2m) {
            asm volatile("global_store_dwordx2 %0, %1, off sc0"
                         :: "v"(dst2), "v"(pk) : "memory");
          } else {
            __hip_atomic_store(dst2, pk, __ATOMIC_RELAXED, __HIP_MEMORY_SCOPE_AGENT);
          }
          __hip_atomic_store(&h_hist[(uint64_t)(s & 511) * 256 + jglob], pk,
                             __ATOMIC_RELAXED, __HIP_MEMORY_SCOPE_AGENT);
        }
      }
    }
  }
}

extern "C" void kernel_launch(void* const* d_in, const int* in_sizes, int n_in,
                              void* d_out, int out_size, void* d_ws, size_t ws_size,
                              hipStream_t stream) {
  const float* W_ih  = (const float*)d_in[0];
  const float* W_hh  = (const float*)d_in[1];
  const float* b_ih  = (const float*)d_in[2];
  const float* b_hh  = (const float*)d_in[3];
  const float* W_out = (const float*)d_in[4];
  const float* b_out = (const float*)d_in[5];
  float* out = (float*)d_out;
  uint64_t* ws = (uint64_t*)d_ws;

  // Zero the ctrl region (p_prog..test_a, 512 B at u64 offset 512*256+1024)
  // AND the h_l2 ring (16 KB right after it), in stream order before the
  // kernel: every dispatch starts from clean election state and fresh ring
  // tags regardless of workspace persistence. Stream-ordered + capturable.
  void* ctrl = (void*)(ws + 512 * 256 + 1024);
  hipMemsetAsync(ctrl, 0, 512 + 8 * 256 * 8, stream);

  arlstm_kernel<<<dim3(NCAND + 1), dim3(256), 0, stream>>>(
      W_ih, W_hh, b_ih, b_hh, W_out, b_out, out, ws);
}

// Round 7
// 35151.730 us; speedup vs baseline: 3.7880x; 3.7880x over previous
//
#include <hip/hip_runtime.h>
#include <stdint.h>

// AutoRegressiveModel: 47 outer x 512 inner sequential LSTM steps (mid=256),
// Bernoulli sampling bit-matches JAX threefry2x32 (partitionable mode).
//
// R9 = R8 (same-XCD L2 h-exchange) with R8's diagnosed failure fixed.
// R8 evidence: passed @133ms, FETCH_SIZE 214->49MB => sc0 polls hit a stale
// local line forever; h discovered only via the 32-spin agent escape. Root
// cause candidates: numeric hwreg(20) not reading XCC_ID (m09 verified the
// SYMBOLIC name only) -> workers scattered across XCDs; and a self-test that
// stored tokens before first read (startup skew) so it couldn't detect the
// stale-line mode. Fixes:
//  - s_getreg hwreg(HW_REG_XCC_ID) symbolic (HW-verified form).
//  - strict 6-round ping-pong self-test: poll-all-THEN-store each round
//    (re-reads an already-cached line 5x = the production pattern), 50us
//    per-poll timeout + 200us total budget via s_memrealtime (100MHz).
//    Eviction-based or broken propagation cannot pass; genuine same-XCD L2
//    exchange finishes in ~30us. Any anomaly -> unanimous agent fallback.
//  - fallback poll restored to R5's 4-deep pipelined spin (R8 fallback was
//    serialized); l2m escape cadence 32 -> 16 spins.
// Worker arithmetic identical to R2/R5 (absmax-stable).

#define MID      256
#define NOUT     48
#define NSEQ     512
#define NOUTER   47
#define NSTEP    (NOUTER * NSEQ)   // 24064
#define NBLK     16
#define NCAND    128
#define MAGIC_V  0x1234ABCDu
#define LOG2E    1.4426950408889634f

typedef __attribute__((ext_vector_type(4))) float f32x4;

#define LD_REL(p) __hip_atomic_load((p), __ATOMIC_RELAXED, __HIP_MEMORY_SCOPE_AGENT)

// LDS-only barrier: order LDS ops before the barrier, skip vmcnt drain.
#define LDS_BARRIER() do {                                          \
    asm volatile("s_waitcnt lgkmcnt(0)\n\ts_barrier" ::: "memory"); \
    __builtin_amdgcn_sched_barrier(0);                              \
  } while (0)

__device__ __forceinline__ uint32_t rotl32(uint32_t x, int d) {
  return (x << d) | (x >> (32 - d));
}

// Exact JAX threefry2x32 (20 rounds).
__device__ __forceinline__ void threefry2x32(uint32_t k0, uint32_t k1,
                                             uint32_t x0, uint32_t x1,
                                             uint32_t& o0, uint32_t& o1) {
  uint32_t ks2 = k0 ^ k1 ^ 0x1BD11BDAu;
  uint32_t v0 = x0 + k0, v1 = x1 + k1;
#define TF_R(r) { v0 += v1; v1 = rotl32(v1, r); v1 ^= v0; }
  TF_R(13) TF_R(15) TF_R(26) TF_R(6)
  v0 += k1;  v1 += ks2 + 1u;
  TF_R(17) TF_R(29) TF_R(16) TF_R(24)
  v0 += ks2; v1 += k0 + 2u;
  TF_R(13) TF_R(15) TF_R(26) TF_R(6)
  v0 += k0;  v1 += k1 + 3u;
  TF_R(17) TF_R(29) TF_R(16) TF_R(24)
  v0 += k1;  v1 += ks2 + 4u;
  TF_R(13) TF_R(15) TF_R(26) TF_R(6)
  v0 += ks2; v1 += k0 + 5u;
#undef TF_R
  o0 = v0; o1 = v1;
}

// Accurate sigmoid for the sampler (off critical path).
__device__ __forceinline__ float sigf(float x) { return 1.0f / (1.0f + expf(-x)); }

__device__ __forceinline__ uint64_t packht(float h, uint32_t tag) {
  return ((uint64_t)tag << 32) | (uint64_t)__float_as_uint(h);
}

__device__ __forceinline__ uint32_t sc0_load32(const uint32_t* p) {
  uint32_t v;
  asm volatile("global_load_dword %0, %1, off sc0\n\ts_waitcnt vmcnt(0)"
               : "=v"(v) : "v"(p) : "memory");
  return v;
}
__device__ __forceinline__ void sc0_store32(uint32_t* p, uint32_t v) {
  asm volatile("global_store_dword %0, %1, off sc0\n\ts_waitcnt vmcnt(0)"
               :: "v"(p), "v"(v) : "memory");
}

__global__ __launch_bounds__(256, 1)
void arlstm_kernel(const float* __restrict__ W_ih, const float* __restrict__ W_hh,
                   const float* __restrict__ b_ih, const float* __restrict__ b_hh,
                   const float* __restrict__ W_out, const float* __restrict__ b_out,
                   float* __restrict__ out, uint64_t* __restrict__ ws) {
  // ws layout (u64 units):
  //   [0, 131072)       h_hist [512][256] tagged (agent; sampler path)
  //   [131072, 132096)  obsbuf [2][512][2] f32
  //   [132096, 132160)  ctrl: p_prog[4], magic, cand_cnt[8], winner, salt,
  //                     verdict[16], test_a[16]   (512 B, memset-cleared)
  //   [132160, 134208)  h_l2 [8][256] tagged ring (sc0 world, memset-cleared)
  uint64_t* h_hist = ws;
  float*    obsbuf = (float*)(ws + 512 * 256);
  uint32_t* p_prog = (uint32_t*)(ws + 512 * 256 + 1024);
  uint32_t* magic    = p_prog + 16;
  uint32_t* cand_cnt = p_prog + 17;                       // [8] per-XCD claims
  int*      winner_p = (int*)(p_prog + 25);               // 0=unset, else xcd+1
  uint32_t* salt_p   = p_prog + 26;                       // per-dispatch salt
  uint32_t* verdict  = p_prog + 27;                       // [16] 0=?,1=ok,2=fail
  uint32_t* test_a   = p_prog + 43;                       // [16] sc0 test tokens
  uint64_t* ob64     = (uint64_t*)obsbuf;                 // pair view (8B aligned)
  uint64_t* h_l2     = ws + 512 * 256 + 1024 + 64;        // [8][256] tagged

  const int tid = threadIdx.x;

  __shared__ __align__(16) float hstage[256];
  __shared__ float plds[4][64];
  __shared__ float ring[2][16][2];
  __shared__ float lp_acc[512];
  __shared__ float ent_acc[512];
  __shared__ float red[256];
  __shared__ int role_sh, mode_sh;

  if (blockIdx.x == 0) {
    // ----------------------- init + sampler block -----------------------
    // (ctrl + h_l2 already zeroed by hipMemsetAsync before this kernel)
    __hip_atomic_store(&h_hist[tid], 0ull, __ATOMIC_RELAXED, __HIP_MEMORY_SCOPE_AGENT);
    if (tid == 0)
      __hip_atomic_store(salt_p, (uint32_t)__builtin_amdgcn_s_memrealtime() | 1u,
                         __ATOMIC_RELAXED, __HIP_MEMORY_SCOPE_AGENT);
    out[(tid)       * NOUT] = 0.0f;   // samples column 0 = zeros
    out[(tid + 256) * NOUT] = 0.0f;
    lp_acc[tid] = 0.0f;  lp_acc[tid + 256] = 0.0f;
    ent_acc[tid] = 0.0f; ent_acc[tid + 256] = 0.0f;
    __threadfence();
    __syncthreads();
    if (tid == 0)
      __hip_atomic_store(magic, MAGIC_V, __ATOMIC_RELEASE, __HIP_MEMORY_SCOPE_AGENT);

    const int w    = tid >> 6;   // wave 0..3 handles steps s with (s-1)&3 == w
    const int lane = tid & 63;
    const float wo0 = W_out[lane * 4 + 0], wo1 = W_out[lane * 4 + 1];
    const float wo2 = W_out[lane * 4 + 2], wo3 = W_out[lane * 4 + 3];
    const float bo = b_out[0];

    for (int s = w + 1; s <= NSTEP; s += 4) {
      const int k = (s - 1) >> 9;
      const int t = (s - 1) & 511;
      uint64_t* src = h_hist + (uint64_t)(s & 511) * 256 + lane * 4;
      uint64_t v0, v1, v2, v3;
      for (;;) {
        v0 = LD_REL(src + 0);
        v1 = LD_REL(src + 1);
        v2 = LD_REL(src + 2);
        v3 = LD_REL(src + 3);
        int ok = ((uint32_t)(v0 >> 32) == (uint32_t)s) &
                 ((uint32_t)(v1 >> 32) == (uint32_t)s) &
                 ((uint32_t)(v2 >> 32) == (uint32_t)s) &
                 ((uint32_t)(v3 >> 32) == (uint32_t)s);
        if (__all(ok)) break;
      }
      float zp = fmaf(__uint_as_float((uint32_t)v0), wo0,
                 fmaf(__uint_as_float((uint32_t)v1), wo1,
                 fmaf(__uint_as_float((uint32_t)v2), wo2,
                      __uint_as_float((uint32_t)v3) * wo3)));
      zp += __shfl_xor(zp, 1);
      zp += __shfl_xor(zp, 2);
      zp += __shfl_xor(zp, 4);
      zp += __shfl_xor(zp, 8);
      zp += __shfl_xor(zp, 16);
      zp += __shfl_xor(zp, 32);
      const float p = sigf(zp + bo);

      // JAX partitionable threefry: key_k = tf((0,42),(0,k)); bits = xor of
      // tf(key_k,(0,t)); u = bitcast((bits>>9)|0x3f800000)-1; sample = u < p.
      uint32_t ka, kb, c1, c2;
      threefry2x32(0u, 42u, 0u, (uint32_t)k, ka, kb);
      threefry2x32(ka, kb, 0u, (uint32_t)t, c1, c2);
      const uint32_t bits = c1 ^ c2;
      const float u = __uint_as_float((bits >> 9) | 0x3f800000u) - 1.0f;
      const float smp = (u < p) ? 1.0f : 0.0f;

      if (lane == 0) {
        uint32_t* ob = (uint32_t*)(obsbuf + ((k + 1) & 1) * (512 * 2) + t * 2);
        __hip_atomic_store(&ob[0], __float_as_uint(smp), __ATOMIC_RELAXED, __HIP_MEMORY_SCOPE_AGENT);
        __hip_atomic_store(&ob[1], __float_as_uint(p),   __ATOMIC_RELAXED, __HIP_MEMORY_SCOPE_AGENT);
        __hip_atomic_store(&p_prog[w], (uint32_t)s, __ATOMIC_RELEASE, __HIP_MEMORY_SCOPE_AGENT);
        out[t * NOUT + (k + 1)] = smp;
        const float lg = logf(p), lg1 = log1pf(-p);
        lp_acc[t]  += (smp > 0.5f) ? lg : lg1;
        ent_acc[t] -= (p * lg + (1.0f - p) * lg1);
      }
    }
    __syncthreads();
    // final outputs: logprobs (centered), entropies (mean over 47)
    red[tid] = lp_acc[tid] + lp_acc[tid + 256];
    __syncthreads();
    for (int off = 128; off > 0; off >>= 1) {
      if (tid < off) red[tid] += red[tid + off];
      __syncthreads();
    }
    const float mean = red[0] * (1.0f / 512.0f);
    out[24576 + tid]        = lp_acc[tid]        - mean;
    out[24576 + 256 + tid]  = lp_acc[tid + 256]  - mean;
    out[25088 + tid]        = ent_acc[tid]       * (1.0f / 47.0f);
    out[25088 + 256 + tid]  = ent_acc[tid + 256] * (1.0f / 47.0f);
  } else {
    // ----------------- worker candidate: claim a co-located slot -----------------
    if (tid == 0) {
      while (__hip_atomic_load(magic, __ATOMIC_ACQUIRE, __HIP_MEMORY_SCOPE_AGENT) != MAGIC_V) {}
      uint32_t xcd;
      asm volatile("s_getreg_b32 %0, hwreg(HW_REG_XCC_ID)" : "=s"(xcd));
      xcd &= 7u;
      int idx = (int)atomicAdd(&cand_cnt[xcd], 1u);
      int role = -1;
      if (idx < NBLK) {
        if (idx == NBLK - 1) atomicCAS(winner_p, 0, (int)xcd + 1);  // 0 = unset
        int wv;
        while ((wv = (int)__hip_atomic_load((uint32_t*)winner_p, __ATOMIC_ACQUIRE,
                                            __HIP_MEMORY_SCOPE_AGENT)) == 0) {}
        if (wv == (int)xcd + 1) role = idx;
      }
      role_sh = role;
    }
    __syncthreads();
    const int blk = role_sh;
    if (blk < 0) return;                // loser block: free the CU

    // ---- STRICT sc0 self-test: 6 ping-pong rounds, poll-all-THEN-store ----
    // Exercises the production pattern (re-read an already-cached line after
    // a remote update) 5x in steady state, under a hard latency budget.
    if (tid == 0) {
      const uint32_t salt = LD_REL(salt_p) | 1u;
#define TTOK(rr2, j) ((salt + (uint32_t)(rr2) * 0x01000193u) ^ ((uint32_t)((j) + 1) * 0x9E3779B9u))
      int ok = 1;
      const uint64_t T0 = __builtin_amdgcn_s_memrealtime();   // 100 MHz ticks
      sc0_store32(&test_a[blk], TTOK(0, blk));
      for (int rr2 = 1; rr2 <= 6 && ok; ++rr2) {
        for (int j = 0; j < NBLK && ok; ++j) {
          const uint32_t want = TTOK(rr2 - 1, j);
          const uint64_t tp = __builtin_amdgcn_s_memrealtime();
          for (;;) {
            if (sc0_load32(&test_a[j]) == want) break;
            if (__builtin_amdgcn_s_memrealtime() - tp > 5000ull) { ok = 0; break; }  // 50 us
          }
        }
        if (ok) sc0_store32(&test_a[blk], TTOK(rr2, blk));
      }
      if (__builtin_amdgcn_s_memrealtime() - T0 > 20000ull) ok = 0;   // 200 us total
#undef TTOK
      __hip_atomic_store(&verdict[blk], ok ? 1u : 2u, __ATOMIC_RELEASE, __HIP_MEMORY_SCOPE_AGENT);
      uint32_t bad = 0;
      for (int j = 0; j < NBLK; ++j) {
        uint32_t vv;
        while ((vv = __hip_atomic_load(&verdict[j], __ATOMIC_ACQUIRE,
                                       __HIP_MEMORY_SCOPE_AGENT)) == 0u) {}
        if (vv == 2u) bad = 1;
      }
      mode_sh = bad ? 0 : 1;
    }
    __syncthreads();
    const bool l2m = (mode_sh != 0);    // true: same-XCD L2 exchange via sc0

    // --------------------------- LSTM worker ---------------------------
    const int part = tid >> 6;          // wave id = column quarter 0..3
    const int r    = tid & 63;          // local row (gate*16 + jloc)
    const int gate = r >> 4;
    const int jloc = r & 15;
    const int row  = gate * 256 + blk * 16 + jloc;

    // W_hh slice in true VGPRs (asm pin prevents rematerialized reloads).
    f32x4 w4[16];
    const f32x4* wsrc = (const f32x4*)(W_hh + row * 256 + part * 64);
#pragma unroll
    for (int i = 0; i < 16; ++i) w4[i] = wsrc[i];
#pragma unroll
    for (int i = 0; i < 16; ++i) asm volatile("" : "+v"(w4[i]));

    // Per-lane epilogue constants (lanes 0..63: lane = gate*16 + j).
    float bb = 0.f, wx0 = 0.f, wx1 = 0.f, mconst = 0.f, ml = 0.f, ad = 0.f;
    if (tid < 64) {
      const int g4 = tid >> 4;
      const int rr = g4 * 256 + blk * 16 + (tid & 15);
      bb  = b_ih[rr] + b_hh[rr];
      wx0 = W_ih[rr * 2 + 0];
      wx1 = W_ih[rr * 2 + 1];
      mconst = (g4 == 2) ? (-2.0f * LOG2E) : (-LOG2E);  // act = ml*sig(sc*x)+ad
      ml     = (g4 == 2) ? 2.0f : 1.0f;
      ad     = (g4 == 2) ? -1.0f : 0.0f;
    }

    if (tid < 16) {  // obs ring: batch 0 (k=0) is all zeros
      ring[0][tid][0] = 0.f; ring[0][tid][1] = 0.f;
      ring[1][tid][0] = 0.f; ring[1][tid][1] = 0.f;
    }
    __syncthreads();

    float c_st = 0.0f;                      // cell state (lanes 0..15)
    const int jglob = blk * 16 + (tid & 15);
    const bool own = (tid >= blk * 16) && (tid < blk * 16 + 16);

    // obs prefetch pipeline state (wave 3, lanes 0..15)
    int      pf_tgt = 0, pf_need = 0;
    uint32_t pf_ppv = 0;
    uint64_t pf_ov  = 0;

    for (int s = 1; s <= NSTEP; ++s) {
      const int ph = (s - 1) & 15;

      // ---- obs prefetch machinery: 3-phase, once per 16 steps (wave 3) ----
      if (part == 3) {
        if (ph == 0) {
          // target steps s+16 .. s+31 (next batch); lane L -> s+16+L
          pf_tgt  = s + 16 + r;
          pf_need = 0;
          if (r < 16 && pf_tgt > NSEQ && pf_tgt <= NSTEP) {
            pf_need = pf_tgt - NSEQ;                 // sampler step required
            pf_ppv  = LD_REL(&p_prog[(pf_need - 1) & 3]);
          }
        } else if (ph == 1) {
          bool ok = (pf_need == 0) || (pf_ppv >= (uint32_t)pf_need);
          while (!__all(ok)) {                       // essentially never taken
            if (!ok) pf_ppv = LD_REL(&p_prog[(pf_need - 1) & 3]);
            ok = (pf_need == 0) || (pf_ppv >= (uint32_t)pf_need);
          }
          pf_ov = 0;
          if (r < 16 && pf_need != 0) {              // flag seen -> data safe
            const int kk = (pf_tgt - 1) >> 9;
            const int tt = (pf_tgt - 1) & 511;
            pf_ov = LD_REL(ob64 + (kk & 1) * 512 + tt);
          }
        } else if (ph == 2) {
          if (r < 16) {
            const int par = (((s - 3) >> 4) + 1) & 1;   // parity of batch b+1
            ring[par][r][0] = __uint_as_float((uint32_t)pf_ov);
            ring[par][r][1] = __uint_as_float((uint32_t)(pf_ov >> 32));
          }
        }
      }

      // ---- stage h_{s-1} ----
      // (own-block words arrive via LDS short-circuit; h_0 is all zeros)
      if (s == 1) {
        hstage[tid] = 0.0f;
      } else if (!own) {
        const uint32_t want = (uint32_t)(s - 1);
        uint64_t v;
        if (l2m) {
          // L2-latency serialized probe of the depth-8 sc0 ring; agent-copy
          // escape every 16 spins guarantees liveness in all circumstances.
          const uint64_t* src  = h_l2 + (uint64_t)((s - 1) & 7) * 256 + tid;
          const uint64_t* srcA = h_hist + (uint64_t)((s - 1) & 511) * 256 + tid;
          int spins = 0;
          for (;;) {
            asm volatile("global_load_dwordx2 %0, %1, off sc0\n\ts_waitcnt vmcnt(0)"
                         : "=v"(v) : "v"(src) : "memory");
            if ((uint32_t)(v >> 32) == want) break;
            if (((++spins) & 15) == 0) {
              v = LD_REL(srcA);
              if ((uint32_t)(v >> 32) == want) break;
            }
          }
        } else {
          // agent fallback: R5's 4-deep pipelined spin
          uint64_t* srcA = h_hist + (uint64_t)((s - 1) & 511) * 256 + tid;
          v = LD_REL(srcA);
          if ((uint32_t)(v >> 32) != want) {
            uint64_t q0 = LD_REL(srcA), q1 = LD_REL(srcA);
            uint64_t q2 = LD_REL(srcA), q3 = LD_REL(srcA);
            for (;;) {
              if ((uint32_t)(q0 >> 32) == want) { v = q0; break; }
              q0 = LD_REL(srcA);
              if ((uint32_t)(q1 >> 32) == want) { v = q1; break; }
              q1 = LD_REL(srcA);
              if ((uint32_t)(q2 >> 32) == want) { v = q2; break; }
              q2 = LD_REL(srcA);
              if ((uint32_t)(q3 >> 32) == want) { v = q3; break; }
              q3 = LD_REL(srcA);
            }
          }
        }
        hstage[tid] = __uint_as_float((uint32_t)v);
      }
      LDS_BARRIER();   // barrier 1: hstage ready (LDS only, no vmcnt drain)

      float a0 = 0.f, a1 = 0.f, a2 = 0.f, a3 = 0.f;
      const f32x4* hs4 = (const f32x4*)(hstage + part * 64);
#pragma unroll
      for (int i = 0; i < 16; ++i) {
        const f32x4 hv = hs4[i];           // same-address broadcast read
        a0 = fmaf(w4[i][0], hv[0], a0);
        a1 = fmaf(w4[i][1], hv[1], a1);
        a2 = fmaf(w4[i][2], hv[2], a2);
        a3 = fmaf(w4[i][3], hv[3], a3);
      }
      plds[part][r] = (a0 + a1) + (a2 + a3);
      LDS_BARRIER();   // barrier 2: plds ready (LDS only)

      if (tid < 64) {
        // One gate per lane: gv = full gate pre-activation.
        const float sx = ring[((s - 1) >> 4) & 1][ph][0];
        const float px = ring[((s - 1) >> 4) & 1][ph][1];
        const float base = wx0 * sx + wx1 * px + bb;
        const float gv = ((plds[0][tid] + plds[1][tid]) +
                          (plds[2][tid] + plds[3][tid])) + base;
        // act = sig(gv) for gates i,f,o; tanh(gv) = 2*sig(2gv)-1 for gate g.
        const float e   = __builtin_amdgcn_exp2f(gv * mconst);
        const float y   = __builtin_amdgcn_rcpf(1.0f + e);
        const float act = __builtin_fmaf(ml, y, ad);
        const int j = tid & 15;
        const float a_f = __shfl(act, j + 16, 64);
        const float a_g = __shfl(act, j + 32, 64);
        const float a_o = __shfl(act, j + 48, 64);
        if (tid < 16) {
          const float t1 = a_f * c_st;
          const float t2 = act * a_g;     // act = sig(i) on lanes 0..15
          c_st = t1 + t2;
          const float ec = __builtin_amdgcn_exp2f(c_st * (-2.0f * LOG2E));
          const float yc = __builtin_amdgcn_rcpf(1.0f + ec);
          const float th = __builtin_fmaf(2.0f, yc, -1.0f);
          const float hnew = a_o * th;
          hstage[jglob] = hnew;           // own-block short-circuit (WAR-safe:
                                          // all step-s reads drained at barrier2)
          const uint64_t pk = packht(hnew, (uint32_t)s);
          uint64_t* dst2 = h_l2 + (uint64_t)(s & 7) * 256 + jglob;
          if (l2m) {
            asm volatile("global_store_dwordx2 %0, %1, off sc0"
                         :: "v"(dst2), "v"(pk) : "memory");
          }
          __hip_atomic_store(&h_hist[(uint64_t)(s & 511) * 256 + jglob], pk,
                             __ATOMIC_RELAXED, __HIP_MEMORY_SCOPE_AGENT);
        }
      }
    }
  }
}

extern "C" void kernel_launch(void* const* d_in, const int* in_sizes, int n_in,
                              void* d_out, int out_size, void* d_ws, size_t ws_size,
                              hipStream_t stream) {
  const float* W_ih  = (const float*)d_in[0];
  const float* W_hh  = (const float*)d_in[1];
  const float* b_ih  = (const float*)d_in[2];
  const float* b_hh  = (const float*)d_in[3];
  const float* W_out = (const float*)d_in[4];
  const float* b_out = (const float*)d_in[5];
  float* out = (float*)d_out;
  uint64_t* ws = (uint64_t*)d_ws;

  // Zero the ctrl region (p_prog..test_a, 512 B at u64 offset 512*256+1024)
  // AND the h_l2 ring (16 KB right after it), in stream order before the
  // kernel: every dispatch starts from clean election state and fresh ring
  // tags regardless of workspace persistence. Stream-ordered + capturable.
  void* ctrl = (void*)(ws + 512 * 256 + 1024);
  hipMemsetAsync(ctrl, 0, 512 + 8 * 256 * 8, stream);

  arlstm_kernel<<<dim3(NCAND + 1), dim3(256), 0, stream>>>(
      W_ih, W_hh, b_ih, b_hh, W_out, b_out, out, ws);
}